// Round 18
// baseline (190.839 us; speedup 1.0000x reference)
//
#include <hip/hip_runtime.h>
#include <hip/hip_bf16.h>

#define N_NODES 10000
#define N_EDGES 30000
#define F_NODE  32
#define F_EDGE  8
#define EMB     64
#define HID     16
#define NGRAPH  64
#define NBUCK   625              // 10000/16 exact
#define CAP     128              // slots per src-bucket (mean 48; held r6-r17)
#define NCOL    1088             // 1024 U cols + 64 XB cols (+4 RT tiles separate)
#define ROWW    514              // U_lds row stride in words (514%32=2 -> bank spread; r7-verified)
#define XTS     72               // Xt_bf row stride in shorts (16B-aligned rows, 2-way bank, free)

typedef __attribute__((ext_vector_type(8))) short short8;   // 8 bf16 (MFMA A/B frag)
typedef __attribute__((ext_vector_type(4))) float f32x4;    // MFMA C/D frag

__device__ __forceinline__ unsigned short f2b(float f) {
    __hip_bfloat16 h = __float2bfloat16(f);
    return __builtin_bit_cast(unsigned short, h);
}

struct P {
    const float *x_p, *ea;
    const int *src, *dst, *batch;
    const float *nn0_w1, *nn0_b1, *nn0_w2, *nn0_b2;
    const float *nn1_w1, *nn1_b1, *nn1_w2, *nn1_b2;
    const float *root0, *bias0, *root1, *bias1, *root2, *bias2;
    const float *lin0_w, *lin0_b, *lin1_w, *lin1_b;
    float *out;
    int *cnt, *metap;
    float *A1p;
    unsigned short *W2p0, *W2p1, *RTW0, *RTW1, *RTW2;
    float *AGGa, *AGGb;
};

// ---------------------------------------------------------------------------
// prep (r16-proven): W2p permutes + RTW root-transposes + AGGa zero.
// ---------------------------------------------------------------------------
__global__ void __launch_bounds__(256) k_prep(P p) {
    int b = blockIdx.x, t = threadIdx.x;
    if (b < 136) {                              // W2p0 (K=32): 34816 elems
        int i = b * 256 + t;
        if (i >= NCOL * F_NODE) return;
        int rt = i >> 5, k = i & 31;
        float v;
        if (rt < 1024) {
            int T = rt >> 4, lr = rt & 15;
            int o = ((T >> 4) << 4) + lr, h = T & 15;
            v = p.nn0_w2[h * (F_NODE * EMB) + k * EMB + o];
        } else {
            v = p.nn0_b2[k * EMB + (rt - 1024)];
        }
        p.W2p0[i] = f2b(v);
    } else if (b < 408) {                       // W2p1 (K=64): 69632 elems
        int i = (b - 136) * 256 + t;
        if (i >= NCOL * EMB) return;
        int rt = i >> 6, k = i & 63;
        float v;
        if (rt < 1024) {
            int T = rt >> 4, lr = rt & 15;
            int o = ((T >> 4) << 4) + lr, h = T & 15;
            v = p.nn1_w2[h * (EMB * EMB) + k * EMB + o];
        } else {
            v = p.nn1_b2[k * EMB + (rt - 1024)];
        }
        p.W2p1[i] = f2b(v);
    } else if (b < 416) {                       // RTW0: [col][k], K=32
        int i = (b - 408) * 256 + t;            // i < 2048
        int col = i >> 5, k = i & 31;
        p.RTW0[i] = f2b(p.root0[k * EMB + col]);
    } else if (b < 432) {                       // RTW1: [col][k], K=64
        int i = (b - 416) * 256 + t;            // i < 4096
        int col = i >> 6, k = i & 63;
        p.RTW1[i] = f2b(p.root1[k * EMB + col]);
    } else if (b < 448) {                       // RTW2: [col][k], K=64
        int i = (b - 432) * 256 + t;
        int col = i >> 6, k = i & 63;
        p.RTW2[i] = f2b(p.root2[k * EMB + col]);
    } else {                                    // zero AGGa
        int idx = (b - 448) * 256 + t;
        float4* Z = (float4*)p.AGGa;
        const float4 z4 = {0.f, 0.f, 0.f, 0.f};
        for (int i = idx; i < (N_NODES * EMB) / 4; i += 160 * 256) Z[i] = z4;
    }
}

// ---------------------------------------------------------------------------
// Fused conv kernel, 512 threads, block b owns nodes [16b,16b+16).
// r18 deltas vs r17 (hide the remaining phase-entry latency):
//   - first B-tile (bcur) and f0's A-frag issued BEFORE the scan/prologue:
//     their global-load latency hides under ~2000 cycles of earlier work.
//   - edge loop 2-stage software pipeline: next edge's meta+A LDS broadcasts
//     prefetched while current edge computes (all convs).
// Everything else identical to r17.
// ---------------------------------------------------------------------------
template <int CONV>
__global__ void __launch_bounds__(512) k_fused(P p) {
    constexpr int K = (CONV == 0) ? F_NODE : EMB;
    __shared__ unsigned short U2[16 * 2 * ROWW];   // 32,896 B
    __shared__ float XB_l[16][65];                 //  4,160 B
    __shared__ unsigned short Xt[16][XTS];         //  2,304 B (bf16, CONV>0)
    __shared__ float A0l[CAP][HID];                // edge A rows (all convs)
    __shared__ int lds_e[CAP];                     // f0 only
    __shared__ int meta_l[CAP];
    __shared__ int lcnt;
    const int b = blockIdx.x, t = threadIdx.x;
    const int n0 = b * 16;
    const int w = t >> 6, l = t & 63;
    const int lrow = l & 15, lk4 = l >> 4;
    const size_t base = (size_t)b * CAP;
    int cnt = 0;

    const unsigned short* W2p = (CONV == 0) ? p.W2p0 : p.W2p1;
    const unsigned short* RTW = (CONV == 0) ? p.RTW0 : ((CONV == 1) ? p.RTW1 : p.RTW2);
    const float* bias = (CONV == 0) ? p.bias0 : ((CONV == 1) ? p.bias1 : p.bias2);
    float* aggOut = (CONV == 1) ? p.AGGb : p.AGGa;

#define LOADB(T_, dst_)                                                                \
    do {                                                                               \
        if ((T_) < 68) {                                                               \
            _Pragma("unroll")                                                          \
            for (int kk = 0; kk < K / 32; kk++)                                        \
                dst_[kk] = *reinterpret_cast<const short8*>(                           \
                    W2p + (size_t)((T_) * 16 + lrow) * K + kk * 32 + lk4 * 8);         \
        } else {                                                                       \
            int col_ = ((T_) - 68) * 16 + lrow;                                        \
            _Pragma("unroll")                                                          \
            for (int kk = 0; kk < K / 32; kk++)                                        \
                dst_[kk] = *reinterpret_cast<const short8*>(                           \
                    RTW + (size_t)col_ * K + kk * 32 + lk4 * 8);                       \
        }                                                                              \
    } while (0)

    // ---- EARLY ISSUE (r18): first B-tile; f0's A-frag. Consumed after the
    // scan/prologue barriers — latency fully hidden.
    short8 bcur[K / 32], bnxt[K / 32];
    LOADB(w, bcur);
    short8 afr[K / 32];
    if (CONV == 0) {
        const float* xp = p.x_p + (size_t)(n0 + lrow) * F_NODE + lk4 * 8;
#pragma unroll
        for (int q = 0; q < 8; q++) afr[0][q] = (short)f2b(xp[q]);
    }

    if (CONV == 0) {
        float4* Zb = (float4*)(p.AGGb + (size_t)n0 * EMB);
        const float4 z4 = {0.f, 0.f, 0.f, 0.f};
        for (int idx = t; idx < 16 * EMB / 4; idx += 512) Zb[idx] = z4;
        if (t == 0) lcnt = 0;
        __syncthreads();
        const int4* s4 = (const int4*)p.src;
        for (int i = t; i < N_EDGES / 4; i += 512) {
            int4 v = s4[i];
            int e0 = i * 4;
            if ((v.x >> 4) == b) { int sl = atomicAdd(&lcnt, 1); if (sl < CAP) lds_e[sl] = ((e0    ) << 4) | (v.x & 15); }
            if ((v.y >> 4) == b) { int sl = atomicAdd(&lcnt, 1); if (sl < CAP) lds_e[sl] = ((e0 + 1) << 4) | (v.y & 15); }
            if ((v.z >> 4) == b) { int sl = atomicAdd(&lcnt, 1); if (sl < CAP) lds_e[sl] = ((e0 + 2) << 4) | (v.z & 15); }
            if ((v.w >> 4) == b) { int sl = atomicAdd(&lcnt, 1); if (sl < CAP) lds_e[sl] = ((e0 + 3) << 4) | (v.w & 15); }
        }
        __syncthreads();
        cnt = lcnt; if (cnt > CAP) cnt = CAP;
        if (t == 0) p.cnt[b] = cnt;
        if (t < cnt) {
            int pk = lds_e[t];
            int e = pk >> 4, sloc = pk & 15;
            int mt = p.dst[e] * 16 + sloc;
            meta_l[t] = mt;
            p.metap[base + t] = mt;
            const float4* ea4 = (const float4*)(p.ea + (size_t)e * F_EDGE);
            float4 ef0 = ea4[0], ef1 = ea4[1];
            float fv[F_EDGE] = {ef0.x, ef0.y, ef0.z, ef0.w, ef1.x, ef1.y, ef1.z, ef1.w};
            float a1v[HID];
#pragma unroll
            for (int h = 0; h < HID; h++) {
                float s0 = p.nn0_b1[h], s1 = p.nn1_b1[h];
#pragma unroll
                for (int i = 0; i < F_EDGE; i++) {
                    s0 += fv[i] * p.nn0_w1[i * HID + h];
                    s1 += fv[i] * p.nn1_w1[i * HID + h];
                }
                A0l[t][h] = fmaxf(s0, 0.f);
                a1v[h] = fmaxf(s1, 0.f);
            }
            float4* A1g = (float4*)(p.A1p + (base + t) * HID);
#pragma unroll
            for (int j = 0; j < 4; j++)
                A1g[j] = float4{a1v[4 * j], a1v[4 * j + 1], a1v[4 * j + 2], a1v[4 * j + 3]};
        }
        // A0l/meta_l visibility covered by the post-MFMA __syncthreads
    }

    if (CONV > 0) {      // prologue: X = relu(AGGin); stage edge meta+A to LDS
        cnt = p.cnt[b];
        for (int idx = t; idx < cnt; idx += 512)
            meta_l[idx] = p.metap[base + idx];           // coalesced dwords
        for (int idx = t; idx < cnt * HID; idx += 512)
            ((float*)A0l)[idx] = p.A1p[base * HID + idx]; // coalesced floats
        const float* aggIn = (CONV == 1) ? p.AGGa : p.AGGb;
        for (int idx = t; idx < 16 * 64; idx += 512) {
            int j = idx >> 6, o = idx & 63;
            int n = n0 + j;
            float sv = fmaxf(aggIn[n * EMB + o], 0.f);
            Xt[j][o] = f2b(sv);
            if (CONV == 1) p.AGGa[n * EMB + o] = 0.f;   // re-zero for conv2
        }
        __syncthreads();
    }

    // ---- MFMA: 72 col-tiles, 9 per wave (T = w + 8i), B double-buffered
    if (CONV > 0) {
#pragma unroll
        for (int kk = 0; kk < K / 32; kk++)       // direct b128, no cvt
            afr[kk] = *reinterpret_cast<const short8*>(&Xt[lrow][kk * 32 + lk4 * 8]);
    }
#pragma unroll
    for (int i = 0; i < 9; i++) {
        int T = w + 8 * i;
        if (i < 8) LOADB(T + 8, bnxt);            // prefetch overlaps MFMA+store
        f32x4 acc = {0.f, 0.f, 0.f, 0.f};
#pragma unroll
        for (int kk = 0; kk < K / 32; kk++)
            acc = __builtin_amdgcn_mfma_f32_16x16x32_bf16(afr[kk], bcur[kk], acc, 0, 0, 0);
        if (T < 64) {
            int h = T & 15, hw = h >> 1, hb = h & 1;
            int ob = ((T >> 4) << 4) + lrow;          // this lane's o
#pragma unroll
            for (int r = 0; r < 4; r++)
                U2[(lk4 * 4 + r) * (2 * ROWW) + hw * 128 + ob * 2 + hb] = f2b(acc[r]);
        } else if (T < 68) {
            int col = (T - 64) * 16 + lrow;
#pragma unroll
            for (int r = 0; r < 4; r++)
                XB_l[lk4 * 4 + r][col] = acc[r];
        } else {
            int col = (T - 68) * 16 + lrow;           // = o
            float bo = bias[col];
#pragma unroll
            for (int r = 0; r < 4; r++)
                atomicAdd(&aggOut[(size_t)(n0 + lk4 * 4 + r) * EMB + col], acc[r] + bo);
        }
        if (i < 8) {
#pragma unroll
            for (int kk = 0; kk < K / 32; kk++) bcur[kk] = bnxt[kk];
        }
    }
#undef LOADB
    __syncthreads();

    // ---- edge loop: 2-stage pipeline (prefetch next edge's meta+A in LDS
    // broadcast while current edge computes); 8 waves interleave.
    const int o = l;
    int qi = w;
    if (qi < cnt) {
        int mt = meta_l[qi];
        float4 a0 = ((const float4*)A0l[qi])[0];
        float4 a1 = ((const float4*)A0l[qi])[1];
        float4 a2 = ((const float4*)A0l[qi])[2];
        float4 a3 = ((const float4*)A0l[qi])[3];
        while (true) {
            int qn = qi + 8;
            int mtn = 0;
            float4 b0, b1, b2, b3;
            if (qn < cnt) {                       // prefetch next edge
                mtn = meta_l[qn];
                b0 = ((const float4*)A0l[qn])[0];
                b1 = ((const float4*)A0l[qn])[1];
                b2 = ((const float4*)A0l[qn])[2];
                b3 = ((const float4*)A0l[qn])[3];
            }
            float av[HID];
            av[0]=a0.x; av[1]=a0.y; av[2]=a0.z; av[3]=a0.w;
            av[4]=a1.x; av[5]=a1.y; av[6]=a1.z; av[7]=a1.w;
            av[8]=a2.x; av[9]=a2.y; av[10]=a2.z; av[11]=a2.w;
            av[12]=a3.x; av[13]=a3.y; av[14]=a3.z; av[15]=a3.w;
            int sloc = mt & 15, dd = mt >> 4;
            const unsigned* up = reinterpret_cast<const unsigned*>(U2) + sloc * ROWW + o;
            float m0 = XB_l[sloc][o], m1 = 0.f;
#define ACC2(dst_, wrd, h)                                                            \
            dst_ = fmaf(__builtin_bit_cast(float, (unsigned)(wrd) << 16), av[h], dst_);   \
            dst_ = fmaf(__builtin_bit_cast(float, (unsigned)(wrd) & 0xffff0000u), av[h + 1], dst_);
#pragma unroll
            for (int hh = 0; hh < 4; hh++) {
                unsigned ua = up[hh * 64];                // conflict-free ds_read
                unsigned ub = up[(hh + 4) * 64];
                ACC2(m0, ua, 2 * hh)
                ACC2(m1, ub, 2 * (hh + 4))
            }
#undef ACC2
            atomicAdd(&aggOut[(size_t)dd * EMB + o], m0 + m1);
            if (qn >= cnt) break;
            qi = qn; mt = mtn; a0 = b0; a1 = b1; a2 = b2; a3 = b3;
        }
    }
}

// ---------------------------------------------------------------------------
// Tail (r16-proven): per-graph max pool of relu(AGGa) + head.
// ---------------------------------------------------------------------------
__global__ void __launch_bounds__(512) k_tail(P p) {
    __shared__ unsigned pool[EMB];
    const int g = blockIdx.x, t = threadIdx.x;
    const int w = t >> 6, o = t & 63;
    if (t < EMB) pool[t] = 0u;                    // relu outputs >= 0
    __syncthreads();
    int lo = 0, hi = N_NODES;
    while (lo < hi) { int mid = (lo + hi) >> 1; if (p.batch[mid] < g) lo = mid + 1; else hi = mid; }
    int lo2 = lo, hi2 = N_NODES;
    while (lo2 < hi2) { int mid = (lo2 + hi2) >> 1; if (p.batch[mid] < g + 1) lo2 = mid + 1; else hi2 = mid; }
    float mx = 0.f;
    for (int nn = lo + w; nn < lo2; nn += 8) {    // wave w: every 8th node
        int n = __builtin_amdgcn_readfirstlane(nn);
        mx = fmaxf(mx, fmaxf(p.AGGa[(size_t)n * EMB + o], 0.f));
    }
    atomicMax(&pool[o], __float_as_uint(mx));     // LDS atomic, 8 per column
    __syncthreads();
    if (t < EMB) {                                // wave 0: head
        int o2 = t;
        float h = p.lin0_b[o2];
#pragma unroll 8
        for (int oo = 0; oo < EMB; oo++)
            h += __uint_as_float(pool[oo]) * p.lin0_w[oo * EMB + o2];
        float v = h * p.lin1_w[o2];
#pragma unroll
        for (int off = 32; off; off >>= 1) v += __shfl_down(v, off, 64);
        if (o2 == 0) p.out[g] = v + p.lin1_b[0];
    }
}

extern "C" void kernel_launch(void* const* d_in, const int* in_sizes, int n_in,
                              void* d_out, int out_size, void* d_ws, size_t ws_size,
                              hipStream_t stream) {
    P p;
    p.x_p    = (const float*)d_in[0];
    p.ea     = (const float*)d_in[2];
    const int* eidx = (const int*)d_in[4];
    p.src    = eidx;                   // edge_index_p[0]
    p.dst    = eidx + N_EDGES;         // edge_index_p[1]
    p.batch  = (const int*)d_in[5];
    p.nn0_w1 = (const float*)d_in[6];  p.nn0_b1 = (const float*)d_in[7];
    p.nn0_w2 = (const float*)d_in[8];  p.nn0_b2 = (const float*)d_in[9];
    p.nn1_w1 = (const float*)d_in[10]; p.nn1_b1 = (const float*)d_in[11];
    p.nn1_w2 = (const float*)d_in[12]; p.nn1_b2 = (const float*)d_in[13];
    p.root0  = (const float*)d_in[14]; p.bias0  = (const float*)d_in[15];
    p.root1  = (const float*)d_in[16]; p.bias1  = (const float*)d_in[17];
    p.root2  = (const float*)d_in[18]; p.bias2  = (const float*)d_in[19];
    p.lin0_w = (const float*)d_in[20]; p.lin0_b = (const float*)d_in[21];
    p.lin1_w = (const float*)d_in[22]; p.lin1_b = (const float*)d_in[23];
    p.out    = (float*)d_out;

    // workspace (~11 MB)
    char* ws = (char*)d_ws;
    p.AGGa   = (float*)ws;          ws += (size_t)N_NODES * EMB * 4;
    p.AGGb   = (float*)ws;          ws += (size_t)N_NODES * EMB * 4;
    p.cnt    = (int*)ws;            ws += 2560;      // 625 ints, padded
    p.metap  = (int*)ws;            ws += (size_t)NBUCK * CAP * 4;
    p.A1p    = (float*)ws;          ws += (size_t)NBUCK * CAP * HID * 4;
    p.W2p0   = (unsigned short*)ws; ws += (size_t)NCOL * F_NODE * 2;
    p.W2p1   = (unsigned short*)ws; ws += (size_t)NCOL * EMB * 2;
    p.RTW0   = (unsigned short*)ws; ws += (size_t)EMB * F_NODE * 2;
    p.RTW1   = (unsigned short*)ws; ws += (size_t)EMB * EMB * 2;
    p.RTW2   = (unsigned short*)ws; ws += (size_t)EMB * EMB * 2;

    k_prep<<<608, 256, 0, stream>>>(p);
    k_fused<0><<<NBUCK, 512, 0, stream>>>(p);
    k_fused<1><<<NBUCK, 512, 0, stream>>>(p);
    k_fused<2><<<NBUCK, 512, 0, stream>>>(p);
    k_tail<<<NGRAPH, 512, 0, stream>>>(p);
}

// Round 21
// 180.842 us; speedup vs baseline: 1.0553x; 1.0553x over previous
//
#include <hip/hip_runtime.h>
#include <hip/hip_bf16.h>

#define N_NODES 10000
#define N_EDGES 30000
#define F_NODE  32
#define F_EDGE  8
#define EMB     64
#define HID     16
#define NGRAPH  64
#define NBUCK   625              // 10000/16 exact
#define CAP     128              // slots per src-bucket (mean 48; held r6-r15)
#define NCOL    1088             // 1024 U cols + 64 XB cols (+4 RT tiles separate)
#define ROWW    514              // U_lds row stride in words (514%32=2 -> bank spread; r7-verified)
#define XTS     72               // Xt_bf row stride in shorts (16B-aligned rows, 2-way bank, free)

typedef __attribute__((ext_vector_type(8))) short short8;   // 8 bf16 (MFMA A/B frag)
typedef __attribute__((ext_vector_type(4))) float f32x4;    // MFMA C/D frag

__device__ __forceinline__ unsigned short f2b(float f) {
    __hip_bfloat16 h = __float2bfloat16(f);
    return __builtin_bit_cast(unsigned short, h);
}

struct P {
    const float *x_p, *ea;
    const int *src, *dst, *batch;
    const float *nn0_w1, *nn0_b1, *nn0_w2, *nn0_b2;
    const float *nn1_w1, *nn1_b1, *nn1_w2, *nn1_b2;
    const float *root0, *bias0, *root1, *bias1, *root2, *bias2;
    const float *lin0_w, *lin0_b, *lin1_w, *lin1_b;
    float *out;
    int *cnt, *metap;
    float *A1p;
    unsigned short *W2p0, *W2p1, *RTW0, *RTW1, *RTW2;
    float *AGGa, *AGGb;
};

// ---------------------------------------------------------------------------
// prep: W2p permutes (r10-proven) + RTW root-transposes + AGGa zero.
//   [0,136)    W2p0 (K=32), transposed tile order (r7 conflict fix).
//   [136,408)  W2p1 (K=64), same order.
//   [408,416)  RTW0 = root0^T bf16 [col][k], K=32 (2048 elems).
//   [416,432)  RTW1 = root1^T bf16 [col][k], K=64 (4096 elems).
//   [432,448)  RTW2 = root2^T bf16 [col][k], K=64 (4096 elems).
//   [448,608)  zero AGGa (float4).
// ---------------------------------------------------------------------------
__global__ void __launch_bounds__(256) k_prep(P p) {
    int b = blockIdx.x, t = threadIdx.x;
    if (b < 136) {                              // W2p0 (K=32): 34816 elems
        int i = b * 256 + t;
        if (i >= NCOL * F_NODE) return;
        int rt = i >> 5, k = i & 31;
        float v;
        if (rt < 1024) {
            int T = rt >> 4, lr = rt & 15;
            int o = ((T >> 4) << 4) + lr, h = T & 15;
            v = p.nn0_w2[h * (F_NODE * EMB) + k * EMB + o];
        } else {
            v = p.nn0_b2[k * EMB + (rt - 1024)];
        }
        p.W2p0[i] = f2b(v);
    } else if (b < 408) {                       // W2p1 (K=64): 69632 elems
        int i = (b - 136) * 256 + t;
        if (i >= NCOL * EMB) return;
        int rt = i >> 6, k = i & 63;
        float v;
        if (rt < 1024) {
            int T = rt >> 4, lr = rt & 15;
            int o = ((T >> 4) << 4) + lr, h = T & 15;
            v = p.nn1_w2[h * (EMB * EMB) + k * EMB + o];
        } else {
            v = p.nn1_b2[k * EMB + (rt - 1024)];
        }
        p.W2p1[i] = f2b(v);
    } else if (b < 416) {                       // RTW0: [col][k], K=32
        int i = (b - 408) * 256 + t;            // i < 2048
        int col = i >> 5, k = i & 31;
        p.RTW0[i] = f2b(p.root0[k * EMB + col]);
    } else if (b < 432) {                       // RTW1: [col][k], K=64
        int i = (b - 416) * 256 + t;            // i < 4096
        int col = i >> 6, k = i & 63;
        p.RTW1[i] = f2b(p.root1[k * EMB + col]);
    } else if (b < 448) {                       // RTW2: [col][k], K=64
        int i = (b - 432) * 256 + t;
        int col = i >> 6, k = i & 63;
        p.RTW2[i] = f2b(p.root2[k * EMB + col]);
    } else {                                    // zero AGGa
        int idx = (b - 448) * 256 + t;
        float4* Z = (float4*)p.AGGa;
        const float4 z4 = {0.f, 0.f, 0.f, 0.f};
        for (int i = idx; i < (N_NODES * EMB) / 4; i += 160 * 256) Z[i] = z4;
    }
}

// ---------------------------------------------------------------------------
// Fused conv kernel, 512 threads, block b owns nodes [16b,16b+16).
// r16 key change: ROOT TERM VIA MFMA. 72 col-tiles (9 per wave, was 8.5):
//   T<64  -> U tile (LDS, conflict-free r7 layout)
//   64-67 -> XB tile (LDS)
//   68-71 -> RT tile = X@root; atomicAdd(RT + bias) into THIS conv's AGG
// So AGG accumulates root-term + bias + edge messages, and the NEXT conv's
// prologue is just X = relu(AGG) (2 loads vs ~130 loads + 64 fmas).
// X0/X1 global buffers deleted entirely.
// AGG ping-pong: conv0->AGGa, conv1->AGGb (re-zeroes AGGa), conv2->AGGa.
// ---------------------------------------------------------------------------
template <int CONV>
__global__ void __launch_bounds__(512) k_fused(P p) {
    constexpr int K = (CONV == 0) ? F_NODE : EMB;
    __shared__ unsigned short U2[16 * 2 * ROWW];   // 32,896 B
    __shared__ float XB_l[16][65];                 //  4,160 B
    __shared__ unsigned short Xt[16][XTS];         //  2,304 B (bf16, CONV>0)
    __shared__ float A0l[CAP][HID];                // f0 only (DCE'd in f1/f2)
    __shared__ int lds_e[CAP];
    __shared__ int meta_l[CAP];
    __shared__ int lcnt;
    const int b = blockIdx.x, t = threadIdx.x;
    const int n0 = b * 16;
    const int w = t >> 6, l = t & 63;
    const int lrow = l & 15, lk4 = l >> 4;
    int cnt = 0;

    if (CONV == 0) {
        float4* Zb = (float4*)(p.AGGb + (size_t)n0 * EMB);
        const float4 z4 = {0.f, 0.f, 0.f, 0.f};
        for (int idx = t; idx < 16 * EMB / 4; idx += 512) Zb[idx] = z4;
        if (t == 0) lcnt = 0;
        __syncthreads();
        const int4* s4 = (const int4*)p.src;
        for (int i = t; i < N_EDGES / 4; i += 512) {
            int4 v = s4[i];
            int e0 = i * 4;
            if ((v.x >> 4) == b) { int sl = atomicAdd(&lcnt, 1); if (sl < CAP) lds_e[sl] = ((e0    ) << 4) | (v.x & 15); }
            if ((v.y >> 4) == b) { int sl = atomicAdd(&lcnt, 1); if (sl < CAP) lds_e[sl] = ((e0 + 1) << 4) | (v.y & 15); }
            if ((v.z >> 4) == b) { int sl = atomicAdd(&lcnt, 1); if (sl < CAP) lds_e[sl] = ((e0 + 2) << 4) | (v.z & 15); }
            if ((v.w >> 4) == b) { int sl = atomicAdd(&lcnt, 1); if (sl < CAP) lds_e[sl] = ((e0 + 3) << 4) | (v.w & 15); }
        }
        __syncthreads();
        cnt = lcnt; if (cnt > CAP) cnt = CAP;
        if (t == 0) p.cnt[b] = cnt;
        if (t < cnt) {
            int pk = lds_e[t];
            int e = pk >> 4, sloc = pk & 15;
            int mt = p.dst[e] * 16 + sloc;
            meta_l[t] = mt;
            p.metap[(size_t)b * CAP + t] = mt;
            const float4* ea4 = (const float4*)(p.ea + (size_t)e * F_EDGE);
            float4 ef0 = ea4[0], ef1 = ea4[1];
            float fv[F_EDGE] = {ef0.x, ef0.y, ef0.z, ef0.w, ef1.x, ef1.y, ef1.z, ef1.w};
            float a1v[HID];
#pragma unroll
            for (int h = 0; h < HID; h++) {
                float s0 = p.nn0_b1[h], s1 = p.nn1_b1[h];
#pragma unroll
                for (int i = 0; i < F_EDGE; i++) {
                    s0 += fv[i] * p.nn0_w1[i * HID + h];
                    s1 += fv[i] * p.nn1_w1[i * HID + h];
                }
                A0l[t][h] = fmaxf(s0, 0.f);
                a1v[h] = fmaxf(s1, 0.f);
            }
            float4* A1g = (float4*)(p.A1p + ((size_t)b * CAP + t) * HID);
#pragma unroll
            for (int j = 0; j < 4; j++)
                A1g[j] = float4{a1v[4 * j], a1v[4 * j + 1], a1v[4 * j + 2], a1v[4 * j + 3]};
        }
        // A0l/meta_l visibility covered by the post-MFMA __syncthreads
    }

    if (CONV > 0) {      // prologue: X = relu(AGGin) — root term already in AGG
        const float* aggIn = (CONV == 1) ? p.AGGa : p.AGGb;
        for (int idx = t; idx < 16 * 64; idx += 512) {
            int j = idx >> 6, o = idx & 63;
            int n = n0 + j;
            float sv = fmaxf(aggIn[n * EMB + o], 0.f);
            Xt[j][o] = f2b(sv);
            if (CONV == 1) p.AGGa[n * EMB + o] = 0.f;   // re-zero for conv2
        }
        __syncthreads();
        cnt = p.cnt[b];
    }

    // ---- MFMA: 72 col-tiles, 9 per wave (T = w + 8i)
    short8 afr[K / 32];
    if (CONV == 0) {
        const float* xp = p.x_p + (size_t)(n0 + lrow) * F_NODE + lk4 * 8;
#pragma unroll
        for (int q = 0; q < 8; q++) afr[0][q] = (short)f2b(xp[q]);
    } else {
#pragma unroll
        for (int kk = 0; kk < K / 32; kk++)       // direct b128, no cvt
            afr[kk] = *reinterpret_cast<const short8*>(&Xt[lrow][kk * 32 + lk4 * 8]);
    }
    const unsigned short* W2p = (CONV == 0) ? p.W2p0 : p.W2p1;
    const unsigned short* RTW = (CONV == 0) ? p.RTW0 : ((CONV == 1) ? p.RTW1 : p.RTW2);
    const float* bias = (CONV == 0) ? p.bias0 : ((CONV == 1) ? p.bias1 : p.bias2);
    float* aggOut = (CONV == 1) ? p.AGGb : p.AGGa;
#pragma unroll
    for (int i = 0; i < 9; i++) {
        int T = w + 8 * i;
        short8 bfr[K / 32];
        if (T < 68) {
#pragma unroll
            for (int kk = 0; kk < K / 32; kk++)
                bfr[kk] = *reinterpret_cast<const short8*>(
                    W2p + (size_t)(T * 16 + lrow) * K + kk * 32 + lk4 * 8);
        } else {
            int col = (T - 68) * 16 + lrow;
#pragma unroll
            for (int kk = 0; kk < K / 32; kk++)
                bfr[kk] = *reinterpret_cast<const short8*>(
                    RTW + (size_t)col * K + kk * 32 + lk4 * 8);
        }
        f32x4 acc = {0.f, 0.f, 0.f, 0.f};
#pragma unroll
        for (int kk = 0; kk < K / 32; kk++)
            acc = __builtin_amdgcn_mfma_f32_16x16x32_bf16(afr[kk], bfr[kk], acc, 0, 0, 0);
        if (T < 64) {
            int h = T & 15, hw = h >> 1, hb = h & 1;
            int ob = ((T >> 4) << 4) + lrow;          // this lane's o
#pragma unroll
            for (int r = 0; r < 4; r++)
                U2[(lk4 * 4 + r) * (2 * ROWW) + hw * 128 + ob * 2 + hb] = f2b(acc[r]);
        } else if (T < 68) {
            int col = (T - 64) * 16 + lrow;
#pragma unroll
            for (int r = 0; r < 4; r++)
                XB_l[lk4 * 4 + r][col] = acc[r];
        } else {
            int col = (T - 68) * 16 + lrow;           // = o
            float bo = bias[col];
#pragma unroll
            for (int r = 0; r < 4; r++)
                atomicAdd(&aggOut[(size_t)(n0 + lk4 * 4 + r) * EMB + col], acc[r] + bo);
        }
    }
    __syncthreads();

    // ---- edge loop (8 waves interleave); 2 independent fma chains per edge
    const size_t base = (size_t)b * CAP;
    const int o = l;
#pragma unroll 2
    for (int qi = w; qi < cnt; qi += 8) {
        int q = __builtin_amdgcn_readfirstlane(qi);
        int mt;
        float av[HID];
        if (CONV == 0) {
            mt = meta_l[q];
            const float4* a4 = (const float4*)A0l[q];     // LDS broadcast b128
            float4 u0 = a4[0], u1 = a4[1], u2 = a4[2], u3 = a4[3];
            av[0]=u0.x; av[1]=u0.y; av[2]=u0.z; av[3]=u0.w;
            av[4]=u1.x; av[5]=u1.y; av[6]=u1.z; av[7]=u1.w;
            av[8]=u2.x; av[9]=u2.y; av[10]=u2.z; av[11]=u2.w;
            av[12]=u3.x; av[13]=u3.y; av[14]=u3.z; av[15]=u3.w;
        } else {
            mt = p.metap[base + q];                       // s_load (q uniform)
            const float* Ae = p.A1p + (base + q) * HID;   // contiguous s_loads
#pragma unroll
            for (int h = 0; h < HID; h++) av[h] = Ae[h];
        }
        int sloc = mt & 15, dd = mt >> 4;
        const unsigned* up = reinterpret_cast<const unsigned*>(U2) + sloc * ROWW + o;
        float m0 = XB_l[sloc][o], m1 = 0.f;
#define ACC2(dst_, wrd, h)                                                            \
        dst_ = fmaf(__builtin_bit_cast(float, (unsigned)(wrd) << 16), av[h], dst_);   \
        dst_ = fmaf(__builtin_bit_cast(float, (unsigned)(wrd) & 0xffff0000u), av[h + 1], dst_);
#pragma unroll
        for (int hh = 0; hh < 4; hh++) {
            unsigned ua = up[hh * 64];                    // conflict-free ds_read
            unsigned ub = up[(hh + 4) * 64];
            ACC2(m0, ua, 2 * hh)
            ACC2(m1, ub, 2 * (hh + 4))
        }
#undef ACC2
        atomicAdd(&aggOut[(size_t)dd * EMB + o], m0 + m1);
    }
}

// ---------------------------------------------------------------------------
// Tail: per-graph max pool of relu(AGGa) + head. Root term already folded
// into AGGa by f2's MFMA; no root2 GEMV, no X1 reads. batch sorted ->
// binary-searched node range per graph block.
// ---------------------------------------------------------------------------
__global__ void __launch_bounds__(512) k_tail(P p) {
    __shared__ unsigned pool[EMB];
    const int g = blockIdx.x, t = threadIdx.x;
    const int w = t >> 6, o = t & 63;
    if (t < EMB) pool[t] = 0u;                    // relu outputs >= 0
    __syncthreads();
    int lo = 0, hi = N_NODES;
    while (lo < hi) { int mid = (lo + hi) >> 1; if (p.batch[mid] < g) lo = mid + 1; else hi = mid; }
    int lo2 = lo, hi2 = N_NODES;
    while (lo2 < hi2) { int mid = (lo2 + hi2) >> 1; if (p.batch[mid] < g + 1) lo2 = mid + 1; else hi2 = mid; }
    float mx = 0.f;
    for (int nn = lo + w; nn < lo2; nn += 8) {    // wave w: every 8th node
        int n = __builtin_amdgcn_readfirstlane(nn);
        mx = fmaxf(mx, fmaxf(p.AGGa[(size_t)n * EMB + o], 0.f));
    }
    atomicMax(&pool[o], __float_as_uint(mx));     // LDS atomic, 8 per column
    __syncthreads();
    if (t < EMB) {                                // wave 0: head
        int o2 = t;
        float h = p.lin0_b[o2];
#pragma unroll 8
        for (int oo = 0; oo < EMB; oo++)
            h += __uint_as_float(pool[oo]) * p.lin0_w[oo * EMB + o2];
        float v = h * p.lin1_w[o2];
#pragma unroll
        for (int off = 32; off; off >>= 1) v += __shfl_down(v, off, 64);
        if (o2 == 0) p.out[g] = v + p.lin1_b[0];
    }
}

extern "C" void kernel_launch(void* const* d_in, const int* in_sizes, int n_in,
                              void* d_out, int out_size, void* d_ws, size_t ws_size,
                              hipStream_t stream) {
    P p;
    p.x_p    = (const float*)d_in[0];
    p.ea     = (const float*)d_in[2];
    const int* eidx = (const int*)d_in[4];
    p.src    = eidx;                   // edge_index_p[0]
    p.dst    = eidx + N_EDGES;         // edge_index_p[1]
    p.batch  = (const int*)d_in[5];
    p.nn0_w1 = (const float*)d_in[6];  p.nn0_b1 = (const float*)d_in[7];
    p.nn0_w2 = (const float*)d_in[8];  p.nn0_b2 = (const float*)d_in[9];
    p.nn1_w1 = (const float*)d_in[10]; p.nn1_b1 = (const float*)d_in[11];
    p.nn1_w2 = (const float*)d_in[12]; p.nn1_b2 = (const float*)d_in[13];
    p.root0  = (const float*)d_in[14]; p.bias0  = (const float*)d_in[15];
    p.root1  = (const float*)d_in[16]; p.bias1  = (const float*)d_in[17];
    p.root2  = (const float*)d_in[18]; p.bias2  = (const float*)d_in[19];
    p.lin0_w = (const float*)d_in[20]; p.lin0_b = (const float*)d_in[21];
    p.lin1_w = (const float*)d_in[22]; p.lin1_b = (const float*)d_in[23];
    p.out    = (float*)d_out;

    // workspace (~11 MB). X0/X1 deleted; RTW0/1/2 added (20 KB).
    char* ws = (char*)d_ws;
    p.AGGa   = (float*)ws;          ws += (size_t)N_NODES * EMB * 4;
    p.AGGb   = (float*)ws;          ws += (size_t)N_NODES * EMB * 4;
    p.cnt    = (int*)ws;            ws += 2560;      // 625 ints, padded
    p.metap  = (int*)ws;            ws += (size_t)NBUCK * CAP * 4;
    p.A1p    = (float*)ws;          ws += (size_t)NBUCK * CAP * HID * 4;
    p.W2p0   = (unsigned short*)ws; ws += (size_t)NCOL * F_NODE * 2;
    p.W2p1   = (unsigned short*)ws; ws += (size_t)NCOL * EMB * 2;
    p.RTW0   = (unsigned short*)ws; ws += (size_t)EMB * F_NODE * 2;
    p.RTW1   = (unsigned short*)ws; ws += (size_t)EMB * EMB * 2;
    p.RTW2   = (unsigned short*)ws; ws += (size_t)EMB * EMB * 2;

    k_prep<<<608, 256, 0, stream>>>(p);
    k_fused<0><<<NBUCK, 512, 0, stream>>>(p);
    k_fused<1><<<NBUCK, 512, 0, stream>>>(p);
    k_fused<2><<<NBUCK, 512, 0, stream>>>(p);
    k_tail<<<NGRAPH, 512, 0, stream>>>(p);
}

// Round 22
// 173.056 us; speedup vs baseline: 1.1028x; 1.0450x over previous
//
#include <hip/hip_runtime.h>
#include <hip/hip_bf16.h>

#define N_NODES 10000
#define N_EDGES 30000
#define F_NODE  32
#define F_EDGE  8
#define EMB     64
#define HID     16
#define NGRAPH  64
#define NBUCK   625              // 10000/16 exact
#define CAP     128              // slots per src-bucket (mean 48; held r6-r17)
#define NCOL    1088             // 1024 U cols + 64 XB cols (+4 RT tiles separate)
#define ROWW    514              // U_lds row stride in words (514%32=2 -> bank spread; r7-verified)
#define XTS     72               // Xt_bf row stride in shorts (16B-aligned rows, 2-way bank, free)

typedef __attribute__((ext_vector_type(8))) short short8;   // 8 bf16 (MFMA A/B frag)
typedef __attribute__((ext_vector_type(4))) float f32x4;    // MFMA C/D frag

__device__ __forceinline__ unsigned short f2b(float f) {
    __hip_bfloat16 h = __float2bfloat16(f);
    return __builtin_bit_cast(unsigned short, h);
}

struct P {
    const float *x_p, *ea;
    const int *src, *dst, *batch;
    const float *nn0_w1, *nn0_b1, *nn0_w2, *nn0_b2;
    const float *nn1_w1, *nn1_b1, *nn1_w2, *nn1_b2;
    const float *root0, *bias0, *root1, *bias1, *root2, *bias2;
    const float *lin0_w, *lin0_b, *lin1_w, *lin1_b;
    float *out;
    int *cnt, *metap;
    float *A1p;
    unsigned short *W2p0, *W2p1, *RTW0, *RTW1, *RTW2;
    float *AGGa, *AGGb;
};

// ---------------------------------------------------------------------------
// prep (r16-proven): W2p permutes + RTW root-transposes + AGGa zero.
// ---------------------------------------------------------------------------
__global__ void __launch_bounds__(256) k_prep(P p) {
    int b = blockIdx.x, t = threadIdx.x;
    if (b < 136) {                              // W2p0 (K=32): 34816 elems
        int i = b * 256 + t;
        if (i >= NCOL * F_NODE) return;
        int rt = i >> 5, k = i & 31;
        float v;
        if (rt < 1024) {
            int T = rt >> 4, lr = rt & 15;
            int o = ((T >> 4) << 4) + lr, h = T & 15;
            v = p.nn0_w2[h * (F_NODE * EMB) + k * EMB + o];
        } else {
            v = p.nn0_b2[k * EMB + (rt - 1024)];
        }
        p.W2p0[i] = f2b(v);
    } else if (b < 408) {                       // W2p1 (K=64): 69632 elems
        int i = (b - 136) * 256 + t;
        if (i >= NCOL * EMB) return;
        int rt = i >> 6, k = i & 63;
        float v;
        if (rt < 1024) {
            int T = rt >> 4, lr = rt & 15;
            int o = ((T >> 4) << 4) + lr, h = T & 15;
            v = p.nn1_w2[h * (EMB * EMB) + k * EMB + o];
        } else {
            v = p.nn1_b2[k * EMB + (rt - 1024)];
        }
        p.W2p1[i] = f2b(v);
    } else if (b < 416) {                       // RTW0: [col][k], K=32
        int i = (b - 408) * 256 + t;            // i < 2048
        int col = i >> 5, k = i & 31;
        p.RTW0[i] = f2b(p.root0[k * EMB + col]);
    } else if (b < 432) {                       // RTW1: [col][k], K=64
        int i = (b - 416) * 256 + t;            // i < 4096
        int col = i >> 6, k = i & 63;
        p.RTW1[i] = f2b(p.root1[k * EMB + col]);
    } else if (b < 448) {                       // RTW2: [col][k], K=64
        int i = (b - 432) * 256 + t;
        int col = i >> 6, k = i & 63;
        p.RTW2[i] = f2b(p.root2[k * EMB + col]);
    } else {                                    // zero AGGa
        int idx = (b - 448) * 256 + t;
        float4* Z = (float4*)p.AGGa;
        const float4 z4 = {0.f, 0.f, 0.f, 0.f};
        for (int i = idx; i < (N_NODES * EMB) / 4; i += 160 * 256) Z[i] = z4;
    }
}

// ---------------------------------------------------------------------------
// Fused conv kernel (r17 — best verified, 174.2 us), 512 threads, block b
// owns nodes [16b,16b+16):
//   - 72 MFMA col-tiles incl. root-term (T 68-71 -> atomicAdd RT+bias into
//     this conv's AGG); next conv's prologue = relu(AGG) only.
//   - B-tiles double-buffer prefetched INSIDE the MFMA loop (post-barrier
//     placement; r18's pre-barrier hoist regressed -16 us, reverted).
//   - f1/f2 stage metap+A1p into LDS; edge loop LDS-only for all convs,
//     simple form (r18's 2-stage pipeline regressed, reverted).
//   - U layout word = row*514+(h>>1)*64+o: conflict-free (r7-verified).
// AGG ping-pong: conv0->AGGa, conv1->AGGb (re-zeroes AGGa), conv2->AGGa.
// ---------------------------------------------------------------------------
template <int CONV>
__global__ void __launch_bounds__(512) k_fused(P p) {
    constexpr int K = (CONV == 0) ? F_NODE : EMB;
    __shared__ unsigned short U2[16 * 2 * ROWW];   // 32,896 B
    __shared__ float XB_l[16][65];                 //  4,160 B
    __shared__ unsigned short Xt[16][XTS];         //  2,304 B (bf16, CONV>0)
    __shared__ float A0l[CAP][HID];                // edge A rows (all convs)
    __shared__ int lds_e[CAP];                     // f0 only
    __shared__ int meta_l[CAP];
    __shared__ int lcnt;
    const int b = blockIdx.x, t = threadIdx.x;
    const int n0 = b * 16;
    const int w = t >> 6, l = t & 63;
    const int lrow = l & 15, lk4 = l >> 4;
    const size_t base = (size_t)b * CAP;
    int cnt = 0;

    if (CONV == 0) {
        float4* Zb = (float4*)(p.AGGb + (size_t)n0 * EMB);
        const float4 z4 = {0.f, 0.f, 0.f, 0.f};
        for (int idx = t; idx < 16 * EMB / 4; idx += 512) Zb[idx] = z4;
        if (t == 0) lcnt = 0;
        __syncthreads();
        const int4* s4 = (const int4*)p.src;
        for (int i = t; i < N_EDGES / 4; i += 512) {
            int4 v = s4[i];
            int e0 = i * 4;
            if ((v.x >> 4) == b) { int sl = atomicAdd(&lcnt, 1); if (sl < CAP) lds_e[sl] = ((e0    ) << 4) | (v.x & 15); }
            if ((v.y >> 4) == b) { int sl = atomicAdd(&lcnt, 1); if (sl < CAP) lds_e[sl] = ((e0 + 1) << 4) | (v.y & 15); }
            if ((v.z >> 4) == b) { int sl = atomicAdd(&lcnt, 1); if (sl < CAP) lds_e[sl] = ((e0 + 2) << 4) | (v.z & 15); }
            if ((v.w >> 4) == b) { int sl = atomicAdd(&lcnt, 1); if (sl < CAP) lds_e[sl] = ((e0 + 3) << 4) | (v.w & 15); }
        }
        __syncthreads();
        cnt = lcnt; if (cnt > CAP) cnt = CAP;
        if (t == 0) p.cnt[b] = cnt;
        if (t < cnt) {
            int pk = lds_e[t];
            int e = pk >> 4, sloc = pk & 15;
            int mt = p.dst[e] * 16 + sloc;
            meta_l[t] = mt;
            p.metap[base + t] = mt;
            const float4* ea4 = (const float4*)(p.ea + (size_t)e * F_EDGE);
            float4 ef0 = ea4[0], ef1 = ea4[1];
            float fv[F_EDGE] = {ef0.x, ef0.y, ef0.z, ef0.w, ef1.x, ef1.y, ef1.z, ef1.w};
            float a1v[HID];
#pragma unroll
            for (int h = 0; h < HID; h++) {
                float s0 = p.nn0_b1[h], s1 = p.nn1_b1[h];
#pragma unroll
                for (int i = 0; i < F_EDGE; i++) {
                    s0 += fv[i] * p.nn0_w1[i * HID + h];
                    s1 += fv[i] * p.nn1_w1[i * HID + h];
                }
                A0l[t][h] = fmaxf(s0, 0.f);
                a1v[h] = fmaxf(s1, 0.f);
            }
            float4* A1g = (float4*)(p.A1p + (base + t) * HID);
#pragma unroll
            for (int j = 0; j < 4; j++)
                A1g[j] = float4{a1v[4 * j], a1v[4 * j + 1], a1v[4 * j + 2], a1v[4 * j + 3]};
        }
        // A0l/meta_l visibility covered by the post-MFMA __syncthreads
    }

    if (CONV > 0) {      // prologue: X = relu(AGGin); stage edge meta+A to LDS
        cnt = p.cnt[b];
        for (int idx = t; idx < cnt; idx += 512)
            meta_l[idx] = p.metap[base + idx];           // coalesced dwords
        for (int idx = t; idx < cnt * HID; idx += 512)
            ((float*)A0l)[idx] = p.A1p[base * HID + idx]; // coalesced floats
        const float* aggIn = (CONV == 1) ? p.AGGa : p.AGGb;
        for (int idx = t; idx < 16 * 64; idx += 512) {
            int j = idx >> 6, o = idx & 63;
            int n = n0 + j;
            float sv = fmaxf(aggIn[n * EMB + o], 0.f);
            Xt[j][o] = f2b(sv);
            if (CONV == 1) p.AGGa[n * EMB + o] = 0.f;   // re-zero for conv2
        }
        __syncthreads();
    }

    // ---- MFMA: 72 col-tiles, 9 per wave (T = w + 8i), B double-buffered
    short8 afr[K / 32];
    if (CONV == 0) {
        const float* xp = p.x_p + (size_t)(n0 + lrow) * F_NODE + lk4 * 8;
#pragma unroll
        for (int q = 0; q < 8; q++) afr[0][q] = (short)f2b(xp[q]);
    } else {
#pragma unroll
        for (int kk = 0; kk < K / 32; kk++)       // direct b128, no cvt
            afr[kk] = *reinterpret_cast<const short8*>(&Xt[lrow][kk * 32 + lk4 * 8]);
    }
    const unsigned short* W2p = (CONV == 0) ? p.W2p0 : p.W2p1;
    const unsigned short* RTW = (CONV == 0) ? p.RTW0 : ((CONV == 1) ? p.RTW1 : p.RTW2);
    const float* bias = (CONV == 0) ? p.bias0 : ((CONV == 1) ? p.bias1 : p.bias2);
    float* aggOut = (CONV == 1) ? p.AGGb : p.AGGa;

#define LOADB(T_, dst_)                                                                \
    do {                                                                               \
        if ((T_) < 68) {                                                               \
            _Pragma("unroll")                                                          \
            for (int kk = 0; kk < K / 32; kk++)                                        \
                dst_[kk] = *reinterpret_cast<const short8*>(                           \
                    W2p + (size_t)((T_) * 16 + lrow) * K + kk * 32 + lk4 * 8);         \
        } else {                                                                       \
            int col_ = ((T_) - 68) * 16 + lrow;                                        \
            _Pragma("unroll")                                                          \
            for (int kk = 0; kk < K / 32; kk++)                                        \
                dst_[kk] = *reinterpret_cast<const short8*>(                           \
                    RTW + (size_t)col_ * K + kk * 32 + lk4 * 8);                       \
        }                                                                              \
    } while (0)

    short8 bcur[K / 32], bnxt[K / 32];
    LOADB(w, bcur);
#pragma unroll
    for (int i = 0; i < 9; i++) {
        int T = w + 8 * i;
        if (i < 8) LOADB(T + 8, bnxt);            // prefetch overlaps MFMA+store
        f32x4 acc = {0.f, 0.f, 0.f, 0.f};
#pragma unroll
        for (int kk = 0; kk < K / 32; kk++)
            acc = __builtin_amdgcn_mfma_f32_16x16x32_bf16(afr[kk], bcur[kk], acc, 0, 0, 0);
        if (T < 64) {
            int h = T & 15, hw = h >> 1, hb = h & 1;
            int ob = ((T >> 4) << 4) + lrow;          // this lane's o
#pragma unroll
            for (int r = 0; r < 4; r++)
                U2[(lk4 * 4 + r) * (2 * ROWW) + hw * 128 + ob * 2 + hb] = f2b(acc[r]);
        } else if (T < 68) {
            int col = (T - 64) * 16 + lrow;
#pragma unroll
            for (int r = 0; r < 4; r++)
                XB_l[lk4 * 4 + r][col] = acc[r];
        } else {
            int col = (T - 68) * 16 + lrow;           // = o
            float bo = bias[col];
#pragma unroll
            for (int r = 0; r < 4; r++)
                atomicAdd(&aggOut[(size_t)(n0 + lk4 * 4 + r) * EMB + col], acc[r] + bo);
        }
        if (i < 8) {
#pragma unroll
            for (int kk = 0; kk < K / 32; kk++) bcur[kk] = bnxt[kk];
        }
    }
#undef LOADB
    __syncthreads();

    // ---- edge loop (8 waves interleave); LDS-only edge data for ALL convs
    const int o = l;
#pragma unroll 2
    for (int qi = w; qi < cnt; qi += 8) {
        int q = __builtin_amdgcn_readfirstlane(qi);
        int mt = meta_l[q];
        const float4* a4 = (const float4*)A0l[q];     // LDS broadcast b128
        float4 u0 = a4[0], u1 = a4[1], u2 = a4[2], u3 = a4[3];
        float av[HID];
        av[0]=u0.x; av[1]=u0.y; av[2]=u0.z; av[3]=u0.w;
        av[4]=u1.x; av[5]=u1.y; av[6]=u1.z; av[7]=u1.w;
        av[8]=u2.x; av[9]=u2.y; av[10]=u2.z; av[11]=u2.w;
        av[12]=u3.x; av[13]=u3.y; av[14]=u3.z; av[15]=u3.w;
        int sloc = mt & 15, dd = mt >> 4;
        const unsigned* up = reinterpret_cast<const unsigned*>(U2) + sloc * ROWW + o;
        float m0 = XB_l[sloc][o], m1 = 0.f;
#define ACC2(dst_, wrd, h)                                                            \
        dst_ = fmaf(__builtin_bit_cast(float, (unsigned)(wrd) << 16), av[h], dst_);   \
        dst_ = fmaf(__builtin_bit_cast(float, (unsigned)(wrd) & 0xffff0000u), av[h + 1], dst_);
#pragma unroll
        for (int hh = 0; hh < 4; hh++) {
            unsigned ua = up[hh * 64];                    // conflict-free ds_read
            unsigned ub = up[(hh + 4) * 64];
            ACC2(m0, ua, 2 * hh)
            ACC2(m1, ub, 2 * (hh + 4))
        }
#undef ACC2
        atomicAdd(&aggOut[(size_t)dd * EMB + o], m0 + m1);
    }
}

// ---------------------------------------------------------------------------
// Tail (r16-proven): per-graph max pool of relu(AGGa) + head.
// ---------------------------------------------------------------------------
__global__ void __launch_bounds__(512) k_tail(P p) {
    __shared__ unsigned pool[EMB];
    const int g = blockIdx.x, t = threadIdx.x;
    const int w = t >> 6, o = t & 63;
    if (t < EMB) pool[t] = 0u;                    // relu outputs >= 0
    __syncthreads();
    int lo = 0, hi = N_NODES;
    while (lo < hi) { int mid = (lo + hi) >> 1; if (p.batch[mid] < g) lo = mid + 1; else hi = mid; }
    int lo2 = lo, hi2 = N_NODES;
    while (lo2 < hi2) { int mid = (lo2 + hi2) >> 1; if (p.batch[mid] < g + 1) lo2 = mid + 1; else hi2 = mid; }
    float mx = 0.f;
    for (int nn = lo + w; nn < lo2; nn += 8) {    // wave w: every 8th node
        int n = __builtin_amdgcn_readfirstlane(nn);
        mx = fmaxf(mx, fmaxf(p.AGGa[(size_t)n * EMB + o], 0.f));
    }
    atomicMax(&pool[o], __float_as_uint(mx));     // LDS atomic, 8 per column
    __syncthreads();
    if (t < EMB) {                                // wave 0: head
        int o2 = t;
        float h = p.lin0_b[o2];
#pragma unroll 8
        for (int oo = 0; oo < EMB; oo++)
            h += __uint_as_float(pool[oo]) * p.lin0_w[oo * EMB + o2];
        float v = h * p.lin1_w[o2];
#pragma unroll
        for (int off = 32; off; off >>= 1) v += __shfl_down(v, off, 64);
        if (o2 == 0) p.out[g] = v + p.lin1_b[0];
    }
}

extern "C" void kernel_launch(void* const* d_in, const int* in_sizes, int n_in,
                              void* d_out, int out_size, void* d_ws, size_t ws_size,
                              hipStream_t stream) {
    P p;
    p.x_p    = (const float*)d_in[0];
    p.ea     = (const float*)d_in[2];
    const int* eidx = (const int*)d_in[4];
    p.src    = eidx;                   // edge_index_p[0]
    p.dst    = eidx + N_EDGES;         // edge_index_p[1]
    p.batch  = (const int*)d_in[5];
    p.nn0_w1 = (const float*)d_in[6];  p.nn0_b1 = (const float*)d_in[7];
    p.nn0_w2 = (const float*)d_in[8];  p.nn0_b2 = (const float*)d_in[9];
    p.nn1_w1 = (const float*)d_in[10]; p.nn1_b1 = (const float*)d_in[11];
    p.nn1_w2 = (const float*)d_in[12]; p.nn1_b2 = (const float*)d_in[13];
    p.root0  = (const float*)d_in[14]; p.bias0  = (const float*)d_in[15];
    p.root1  = (const float*)d_in[16]; p.bias1  = (const float*)d_in[17];
    p.root2  = (const float*)d_in[18]; p.bias2  = (const float*)d_in[19];
    p.lin0_w = (const float*)d_in[20]; p.lin0_b = (const float*)d_in[21];
    p.lin1_w = (const float*)d_in[22]; p.lin1_b = (const float*)d_in[23];
    p.out    = (float*)d_out;

    // workspace (~11 MB)
    char* ws = (char*)d_ws;
    p.AGGa   = (float*)ws;          ws += (size_t)N_NODES * EMB * 4;
    p.AGGb   = (float*)ws;          ws += (size_t)N_NODES * EMB * 4;
    p.cnt    = (int*)ws;            ws += 2560;      // 625 ints, padded
    p.metap  = (int*)ws;            ws += (size_t)NBUCK * CAP * 4;
    p.A1p    = (float*)ws;          ws += (size_t)NBUCK * CAP * HID * 4;
    p.W2p0   = (unsigned short*)ws; ws += (size_t)NCOL * F_NODE * 2;
    p.W2p1   = (unsigned short*)ws; ws += (size_t)NCOL * EMB * 2;
    p.RTW0   = (unsigned short*)ws; ws += (size_t)EMB * F_NODE * 2;
    p.RTW1   = (unsigned short*)ws; ws += (size_t)EMB * EMB * 2;
    p.RTW2   = (unsigned short*)ws; ws += (size_t)EMB * EMB * 2;

    k_prep<<<608, 256, 0, stream>>>(p);
    k_fused<0><<<NBUCK, 512, 0, stream>>>(p);
    k_fused<1><<<NBUCK, 512, 0, stream>>>(p);
    k_fused<2><<<NBUCK, 512, 0, stream>>>(p);
    k_tail<<<NGRAPH, 512, 0, stream>>>(p);
}